// Round 3
// baseline (1043.138 us; speedup 1.0000x reference)
//
#include <hip/hip_runtime.h>
#include <cstdint>
#include <cstddef>

#define DEVI __device__ __forceinline__

typedef __bf16 bf16x8 __attribute__((ext_vector_type(8)));
typedef float  floatx4 __attribute__((ext_vector_type(4)));

constexpr int NHEAD = 6;
constexpr int CLF = 64, CHF = 192;
constexpr int IMG = 256;
constexpr int HW  = IMG * IMG;

// LDS pitches (bf16 elements). Row byte-stride must be a multiple of 16
// (ds_read_b128 alignment): 200*2=400, 40*2=80, 72*2=144 all ok.
constexpr int PSTG = 200;  // staging arena pitch (hf_n, later O-staging)
constexpr int PQK  = 40;   // per-head Q,K (64 x 32+8)
constexpr int PVT  = 72;   // V^T (32 x 64+8)
constexpr int PP   = 72;   // lf staging, later P (64 x 64+8)

// LDS arena (bytes). The 25.6KB staging arena is reused three times:
//   phase 1: hf_n staging (LN redistribution)        [B2 .. B2b]
//   phase 2: Q @0, K @5120, VT @10240, rpb @14848    [B2b .. end of heads]
//   phase 3: O-staging, pitch 200                    [epilogue]
constexpr int OFF_Q   = 0;      // 5120
constexpr int OFF_K   = 5120;   // 5120
constexpr int OFF_VT  = 10240;  // 4608
constexpr int OFF_RPB = 14848;  // 2700 (bf16)
constexpr int OFF_LFP = 25600;  // 9216: lf staging, then P
constexpr int OFF_RED = 34816;  // 4096: LN stats (load phase only)
constexpr int SMEM_BYTES = 38912;  // x4 blocks/CU = 155648 <= 163840

DEVI unsigned short f2b(float f) {  // fp32 -> bf16 RNE
  unsigned u = __float_as_uint(f);
  u += 0x7fffu + ((u >> 16) & 1u);
  return (unsigned short)(u >> 16);
}
DEVI float b2f(unsigned short s) { return __uint_as_float(((unsigned)s) << 16); }

DEVI floatx4 mfma_bf16(bf16x8 a, bf16x8 b, floatx4 c) {
  return __builtin_amdgcn_mfma_f32_16x16x32_bf16(a, b, c, 0, 0, 0);
}

// ---- prep: W[k][n] fp32 -> W^T[n][k] bf16 into workspace ----
__global__ void wca_prep(const float* __restrict__ Wq, const float* __restrict__ Wk,
                         const float* __restrict__ Wv, const float* __restrict__ Wo,
                         unsigned short* __restrict__ wT) {
  int i = blockIdx.x * 256 + threadIdx.x;  // grid covers exactly 122880
  if (i < 12288) {                         // WqT: 192 x 64
    int n = i >> 6, k = i & 63;
    wT[i] = f2b(Wq[k * 192 + n]);
  } else if (i < 49152) {                  // WkT: 192 x 192
    int j = i - 12288, n = j / 192, k = j - n * 192;
    wT[i] = f2b(Wk[k * 192 + n]);
  } else if (i < 86016) {                  // WvT
    int j = i - 49152, n = j / 192, k = j - n * 192;
    wT[i] = f2b(Wv[k * 192 + n]);
  } else {                                 // WoT
    int j = i - 86016, n = j / 192, k = j - n * 192;
    wT[i] = f2b(Wo[k * 192 + n]);
  }
}

__global__ __launch_bounds__(256, 4) void wca_main(
    const float* __restrict__ ylf, const float* __restrict__ yhf,
    const float* __restrict__ glf, const float* __restrict__ blf,
    const float* __restrict__ ghf, const float* __restrict__ bhf,
    const float* __restrict__ bq,  const float* __restrict__ bk,
    const float* __restrict__ bv,  const float* __restrict__ bo,
    const float* __restrict__ rpb, const unsigned short* __restrict__ wT,
    float* __restrict__ out) {
  __shared__ __align__(16) char smem[SMEM_BYTES];
  unsigned short* s_stg = (unsigned short*)(smem);            // arena, pitch PSTG
  unsigned short* s_q   = (unsigned short*)(smem + OFF_Q);
  unsigned short* s_k   = (unsigned short*)(smem + OFF_K);
  unsigned short* s_vt  = (unsigned short*)(smem + OFF_VT);
  unsigned short* s_rpb = (unsigned short*)(smem + OFF_RPB);
  unsigned short* s_lf  = (unsigned short*)(smem + OFF_LFP);  // pitch PP
  unsigned short* s_p   = s_lf;                               // P aliases lf (dead after B2b)
  float* s_red = (float*)(smem + OFF_RED);

  const int tid  = threadIdx.x;
  const int lane = tid & 63;
  const int wv   = tid >> 6;     // wave 0..3
  const int quad = lane >> 4;
  const int l16  = lane & 15;

  // XCD-pair swizzle: consecutive blockIdx round-robins the 8 XCDs. Remap so
  // XCD x owns contiguous windows [x*512, +512): wx-adjacent windows (which
  // share every 64B HBM line: window row = 32B) land on the SAME XCD's L2.
  const int g   = blockIdx.x;
  const int wid = ((g & 7) << 9) | (g >> 3);   // 4096 windows, bijective
  const int b   = wid >> 10;
  const int wy  = (wid >> 5) & 31;
  const int wx  = wid & 31;
  const int h0  = wy << 3, w0 = wx << 3;

  const int t_own = tid & 63;          // token owned for load/stats (t = ty*8+tx)
  const int cg    = tid >> 6;          // channel block owner (wave-uniform)
  const int ty    = t_own >> 3, tx = t_own & 7;

  // ---- load windows (coalesced 32B row segments) + LN stats in fp32 ----
  float lfv[16], hfv[48];
  float ls = 0.f, l2 = 0.f, hs = 0.f, h2 = 0.f;
  {
    const float* p = ylf + ((size_t)(b * CLF + cg * 16) * IMG + (h0 + ty)) * IMG + (w0 + tx);
#pragma unroll
    for (int k = 0; k < 16; k++) {
      float v = p[(size_t)k * HW];
      lfv[k] = v; ls += v; l2 += v * v;
    }
  }
  {
    const float* p = yhf + ((size_t)(b * CHF + cg * 48) * IMG + (h0 + ty)) * IMG + (w0 + tx);
#pragma unroll
    for (int k = 0; k < 48; k++) {
      float v = p[(size_t)k * HW];
      hfv[k] = v; hs += v; h2 += v * v;
    }
  }
  s_red[0 * 256 + (cg << 6) + t_own] = ls;
  s_red[1 * 256 + (cg << 6) + t_own] = l2;
  s_red[2 * 256 + (cg << 6) + t_own] = hs;
  s_red[3 * 256 + (cg << 6) + t_own] = h2;
  __syncthreads();  // B1
  float su = 0.f, sq = 0.f, hu = 0.f, hq = 0.f;
#pragma unroll
  for (int gg = 0; gg < 4; gg++) {
    su += s_red[0 * 256 + (gg << 6) + t_own];
    sq += s_red[1 * 256 + (gg << 6) + t_own];
    hu += s_red[2 * 256 + (gg << 6) + t_own];
    hq += s_red[3 * 256 + (gg << 6) + t_own];
  }
  const float mu_lf = su * (1.f / 64.f);
  const float rs_lf = rsqrtf(sq * (1.f / 64.f) - mu_lf * mu_lf + 1e-5f);
  const float mu_hf = hu * (1.f / 192.f);
  const float rs_hf = rsqrtf(hq * (1.f / 192.f) - mu_hf * mu_hf + 1e-5f);

  // normalize + packed u64 bf16 stores
#pragma unroll
  for (int j = 0; j < 4; j++) {
    uint64_t w = 0;
#pragma unroll
    for (int m = 0; m < 4; m++) {
      int c = cg * 16 + j * 4 + m;
      float v = (lfv[j * 4 + m] - mu_lf) * rs_lf * glf[c] + blf[c];
      w |= (uint64_t)f2b(v) << (16 * m);
    }
    *(uint64_t*)(s_lf + t_own * PP + cg * 16 + j * 4) = w;
  }
#pragma unroll
  for (int j = 0; j < 12; j++) {
    uint64_t w = 0;
#pragma unroll
    for (int m = 0; m < 4; m++) {
      int c = cg * 48 + j * 4 + m;
      float v = (hfv[j * 4 + m] - mu_hf) * rs_hf * ghf[c] + bhf[c];
      w |= (uint64_t)f2b(v) << (16 * m);
    }
    *(uint64_t*)(s_stg + t_own * PSTG + cg * 48 + j * 4) = w;
  }
  __syncthreads();  // B2: staging visible to all waves

  // ---- pull this wave's A-fragments into REGISTERS (own 16 rows only) ----
  // lf_n: 2 frags (8 VGPR); hf_n: 6 frags (24 VGPR). After this, both
  // staging buffers are dead and the arena is reused for Q/K/VT/rpb/P.
  bf16x8 lfr0 = *(const bf16x8*)(s_lf + (wv * 16 + l16) * PP + quad * 8);
  bf16x8 lfr1 = *(const bf16x8*)(s_lf + (wv * 16 + l16) * PP + 32 + quad * 8);
  bf16x8 hfr[6];
#pragma unroll
  for (int ks = 0; ks < 6; ks++)
    hfr[ks] = *(const bf16x8*)(s_stg + (wv * 16 + l16) * PSTG + ks * 32 + quad * 8);
  __syncthreads();  // B2b: all frags in regs; arena + lf region reusable

  // stage RPB table as bf16 into the arena (first read is after barrier A of head 0)
  for (int i = tid; i < 225 * NHEAD; i += 256) s_rpb[i] = f2b(rpb[i]);

  const unsigned short* wqT = wT;           // [192][64]
  const unsigned short* wkT = wT + 12288;   // [192][192]
  const unsigned short* wvT = wT + 49152;
  const unsigned short* woT = wT + 86016;

  const int rowbase = wv * 16 + quad * 4;   // C-layout row base for this lane

  // O accumulators live across the whole head loop (48 VGPR)
  floatx4 oa[12];
  const floatx4 zero = {0.f, 0.f, 0.f, 0.f};
#pragma unroll
  for (int ct = 0; ct < 12; ct++) oa[ct] = zero;

  for (int h = 0; h < NHEAD; h++) {
    // ---- Q_h = lf_n @ Wq[:, h*32:+32] + bq (A from registers) ----
#pragma unroll
    for (int nt = 0; nt < 2; nt++) {
      const int n = h * 32 + nt * 16 + l16;
      floatx4 acc = {0.f, 0.f, 0.f, 0.f};
      acc = mfma_bf16(lfr0, *(const bf16x8*)(wqT + n * 64 + quad * 8), acc);
      acc = mfma_bf16(lfr1, *(const bf16x8*)(wqT + n * 64 + 32 + quad * 8), acc);
      const float bqv = bq[n];
#pragma unroll
      for (int r = 0; r < 4; r++)
        s_q[(rowbase + r) * PQK + nt * 16 + l16] = f2b(acc[r] + bqv);
    }
    // ---- K_h (A from registers: no LDS reads in the chain) ----
#pragma unroll
    for (int nt = 0; nt < 2; nt++) {
      const int n = h * 32 + nt * 16 + l16;
      floatx4 acc = {0.f, 0.f, 0.f, 0.f};
#pragma unroll
      for (int ks = 0; ks < 6; ks++)
        acc = mfma_bf16(hfr[ks], *(const bf16x8*)(wkT + n * 192 + ks * 32 + quad * 8), acc);
      const float bkv = bk[n];
#pragma unroll
      for (int r = 0; r < 4; r++)
        s_k[(rowbase + r) * PQK + nt * 16 + l16] = f2b(acc[r] + bkv);
    }
    // ---- V_h (stored transposed: vt[d][m] so PV B-frags are contiguous) ----
#pragma unroll
    for (int nt = 0; nt < 2; nt++) {
      const int n = h * 32 + nt * 16 + l16;
      floatx4 acc = {0.f, 0.f, 0.f, 0.f};
#pragma unroll
      for (int ks = 0; ks < 6; ks++)
        acc = mfma_bf16(hfr[ks], *(const bf16x8*)(wvT + n * 192 + ks * 32 + quad * 8), acc);
      const float bvv = bv[n];
#pragma unroll
      for (int r = 0; r < 4; r++)
        s_vt[(nt * 16 + l16) * PVT + rowbase + r] = f2b(acc[r] + bvv);
    }
    __syncthreads();  // barrier A: K/V (and head-0 rpb) visible to all waves

    // ---- S = Q K^T * scale + rpb bias (wave w owns query rows w*16..+15) ----
    bf16x8 aq = *(const bf16x8*)(s_q + (wv * 16 + l16) * PQK + quad * 8);
    float sv[4][4];
#pragma unroll
    for (int ct = 0; ct < 4; ct++) {
      bf16x8 kb = *(const bf16x8*)(s_k + (ct * 16 + l16) * PQK + quad * 8);
      floatx4 acc = {0.f, 0.f, 0.f, 0.f};
      acc = mfma_bf16(aq, kb, acc);
#pragma unroll
      for (int r = 0; r < 4; r++) {
        int row = rowbase + r, col = ct * 16 + l16;
        int dy = (row >> 3) - (col >> 3) + 7;
        int dx = (row & 7) - (col & 7) + 7;
        sv[ct][r] = acc[r] * 0.17677669529663688f + b2f(s_rpb[(dy * 15 + dx) * NHEAD + h]);
      }
    }
    // ---- softmax over 64 keys: 4 in-lane + xor-shuffle over 16 lanes ----
#pragma unroll
    for (int r = 0; r < 4; r++) {
      float m = fmaxf(fmaxf(sv[0][r], sv[1][r]), fmaxf(sv[2][r], sv[3][r]));
      m = fmaxf(m, __shfl_xor(m, 1));
      m = fmaxf(m, __shfl_xor(m, 2));
      m = fmaxf(m, __shfl_xor(m, 4));
      m = fmaxf(m, __shfl_xor(m, 8));
      const float L2E = 1.4426950408889634f;
      float e0 = exp2f((sv[0][r] - m) * L2E);
      float e1 = exp2f((sv[1][r] - m) * L2E);
      float e2 = exp2f((sv[2][r] - m) * L2E);
      float e3 = exp2f((sv[3][r] - m) * L2E);
      float s = e0 + e1 + e2 + e3;
      s += __shfl_xor(s, 1);
      s += __shfl_xor(s, 2);
      s += __shfl_xor(s, 4);
      s += __shfl_xor(s, 8);
      float inv = 1.f / s;
      sv[0][r] = e0 * inv; sv[1][r] = e1 * inv; sv[2][r] = e2 * inv; sv[3][r] = e3 * inv;
    }
#pragma unroll
    for (int ct = 0; ct < 4; ct++)
#pragma unroll
      for (int r = 0; r < 4; r++)
        s_p[(rowbase + r) * PP + ct * 16 + l16] = f2b(sv[ct][r]);

    // ---- PV: own P rows (same-wave LDS round trip; no barrier needed) ----
    floatx4 pv0 = {0.f, 0.f, 0.f, 0.f}, pv1 = {0.f, 0.f, 0.f, 0.f};
#pragma unroll
    for (int ks = 0; ks < 2; ks++) {
      bf16x8 pa = *(const bf16x8*)(s_p + (wv * 16 + l16) * PP + ks * 32 + quad * 8);
      pv0 = mfma_bf16(pa, *(const bf16x8*)(s_vt + (0 * 16 + l16) * PVT + ks * 32 + quad * 8), pv0);
      pv1 = mfma_bf16(pa, *(const bf16x8*)(s_vt + (1 * 16 + l16) * PVT + ks * 32 + quad * 8), pv1);
    }
    // stage AO_h into s_p cols 0..31 (same-wave DS ops retire in order)
#pragma unroll
    for (int r = 0; r < 4; r++) {
      s_p[(rowbase + r) * PP + l16]      = f2b(pv0[r]);
      s_p[(rowbase + r) * PP + 16 + l16] = f2b(pv1[r]);
    }
    // ---- O += AO_h @ Wo[h*32:(h+1)*32, :]  (register accumulation) ----
    bf16x8 aoh = *(const bf16x8*)(s_p + (wv * 16 + l16) * PP + quad * 8);
#pragma unroll
    for (int ct = 0; ct < 12; ct++) {
      bf16x8 bb = *(const bf16x8*)(woT + (ct * 16 + l16) * 192 + h * 32 + quad * 8);
      oa[ct] = mfma_bf16(aoh, bb, oa[ct]);
    }
    __syncthreads();  // barrier B: next head overwrites Q/K/V/P; last head: epilogue
                      // overwrites the whole arena (Q/K/VT regions) with O-staging
  }

  // ---- epilogue: stage O + bo (compute mapping) into the arena, pitch PSTG ----
#pragma unroll
  for (int ct = 0; ct < 12; ct++) {
    const int col = ct * 16 + l16;
    const float bov = bo[col];
#pragma unroll
    for (int r = 0; r < 4; r++)
      s_stg[(rowbase + r) * PSTG + col] = f2b(oa[ct][r] + bov);
  }
  __syncthreads();  // cross-wave gather follows

  // ---- coalesced store: float4 per lane; residual from coalesced global float4
  // (same addresses as the store -> L3-warm, and pre-warms write-allocate lines) ----
#pragma unroll
  for (int k = 0; k < 12; k++) {
    int chunk = k * 256 + tid;       // 3072 chunks of 4 floats = 192ch x 64tok
    int c   = chunk >> 4;
    int sub = chunk & 15;
    int yy  = sub >> 1;
    int x4  = (sub & 1) << 2;
    int t0  = (yy << 3) + x4;
    size_t gidx = ((size_t)(b * CHF + c) * IMG + (h0 + yy)) * IMG + w0 + x4;
    float4 res = *(const float4*)(yhf + gidx);
    float4 v;
    v.x = b2f(s_stg[(t0 + 0) * PSTG + c]) + res.x;
    v.y = b2f(s_stg[(t0 + 1) * PSTG + c]) + res.y;
    v.z = b2f(s_stg[(t0 + 2) * PSTG + c]) + res.z;
    v.w = b2f(s_stg[(t0 + 3) * PSTG + c]) + res.w;
    *(float4*)(out + gidx) = v;
  }
}

extern "C" void kernel_launch(void* const* d_in, const int* in_sizes, int n_in,
                              void* d_out, int out_size, void* d_ws, size_t ws_size,
                              hipStream_t stream) {
  const float* ylf = (const float*)d_in[0];
  const float* yhf = (const float*)d_in[1];
  const float* glf = (const float*)d_in[2];
  const float* blf = (const float*)d_in[3];
  const float* ghf = (const float*)d_in[4];
  const float* bhf = (const float*)d_in[5];
  const float* Wq  = (const float*)d_in[6];
  const float* bq  = (const float*)d_in[7];
  const float* Wk  = (const float*)d_in[8];
  const float* bk  = (const float*)d_in[9];
  const float* Wv  = (const float*)d_in[10];
  const float* bv  = (const float*)d_in[11];
  const float* Wo  = (const float*)d_in[12];
  const float* bo  = (const float*)d_in[13];
  const float* rpb = (const float*)d_in[14];
  unsigned short* wT = (unsigned short*)d_ws;  // 122880 bf16 = 245760 B

  wca_prep<<<480, 256, 0, stream>>>(Wq, Wk, Wv, Wo, wT);
  wca_main<<<4096, 256, 0, stream>>>(ylf, yhf, glf, blf, ghf, bhf,
                                     bq, bk, bv, bo, rpb, wT, (float*)d_out);
}

// Round 4
// 1007.365 us; speedup vs baseline: 1.0355x; 1.0355x over previous
//
#include <hip/hip_runtime.h>
#include <cstdint>
#include <cstddef>

#define DEVI __device__ __forceinline__

typedef __bf16 bf16x8 __attribute__((ext_vector_type(8)));
typedef float  floatx4 __attribute__((ext_vector_type(4)));

constexpr int NHEAD = 6;
constexpr int CLF = 64, CHF = 192;
constexpr int IMG = 256;
constexpr int HW  = IMG * IMG;

// LDS pitches (bf16 elements). Row byte-stride multiple of 16 (ds_read_b128).
constexpr int PSTG = 200;  // staging arena pitch (hf_n load phase; O staging epilogue)
constexpr int PQK  = 40;   // Q and K tiles (64 x 32+8)
constexpr int PVT  = 72;   // V^T (32 x 64+8)
constexpr int PP   = 72;   // lf staging, later P (64 x 64+8)

// Compute-phase buffers alias the load-phase hf staging arena [0, 25600):
//   Q @0 (wave-private, single), K double-buffered, VT double-buffered.
constexpr int OFF_Q   = 0;      // 5120
constexpr int OFF_K0  = 5120;   // 5120
constexpr int OFF_K1  = 10240;  // 5120
constexpr int OFF_VT0 = 15360;  // 4608
constexpr int OFF_VT1 = 19968;  // 4608  (ends 24576 < 25600)
constexpr int OFF_LFP = 25600;  // 9216: lf staging (load), then P (compute)
constexpr int OFF_RED = 34816;  // 4096: LN stats (load), then rpb bf16 (2700)
constexpr int SMEM_BYTES = 38912;

DEVI unsigned short f2b(float f) {  // fp32 -> bf16 RNE
  unsigned u = __float_as_uint(f);
  u += 0x7fffu + ((u >> 16) & 1u);
  return (unsigned short)(u >> 16);
}
DEVI float b2f(unsigned short s) { return __uint_as_float(((unsigned)s) << 16); }

DEVI floatx4 mfma_bf16(bf16x8 a, bf16x8 b, floatx4 c) {
  return __builtin_amdgcn_mfma_f32_16x16x32_bf16(a, b, c, 0, 0, 0);
}

// ---- prep: W[k][n] fp32 -> W^T[n][k] bf16 into workspace ----
__global__ void wca_prep(const float* __restrict__ Wq, const float* __restrict__ Wk,
                         const float* __restrict__ Wv, const float* __restrict__ Wo,
                         unsigned short* __restrict__ wT) {
  int i = blockIdx.x * 256 + threadIdx.x;  // grid covers exactly 122880
  if (i < 12288) {                         // WqT: 192 x 64
    int n = i >> 6, k = i & 63;
    wT[i] = f2b(Wq[k * 192 + n]);
  } else if (i < 49152) {                  // WkT: 192 x 192
    int j = i - 12288, n = j / 192, k = j - n * 192;
    wT[i] = f2b(Wk[k * 192 + n]);
  } else if (i < 86016) {                  // WvT
    int j = i - 49152, n = j / 192, k = j - n * 192;
    wT[i] = f2b(Wv[k * 192 + n]);
  } else {                                 // WoT
    int j = i - 86016, n = j / 192, k = j - n * 192;
    wT[i] = f2b(Wo[k * 192 + n]);
  }
}

__global__ __launch_bounds__(256, 3) void wca_main(
    const float* __restrict__ ylf, const float* __restrict__ yhf,
    const float* __restrict__ glf, const float* __restrict__ blf,
    const float* __restrict__ ghf, const float* __restrict__ bhf,
    const float* __restrict__ bq,  const float* __restrict__ bk,
    const float* __restrict__ bv,  const float* __restrict__ bo,
    const float* __restrict__ rpb, const unsigned short* __restrict__ wT,
    float* __restrict__ out) {
  __shared__ __align__(16) char smem[SMEM_BYTES];
  unsigned short* s_stg = (unsigned short*)(smem);            // pitch PSTG
  unsigned short* s_q   = (unsigned short*)(smem + OFF_Q);
  unsigned short* s_k0  = (unsigned short*)(smem + OFF_K0);
  unsigned short* s_k1  = (unsigned short*)(smem + OFF_K1);
  unsigned short* s_vt0 = (unsigned short*)(smem + OFF_VT0);
  unsigned short* s_vt1 = (unsigned short*)(smem + OFF_VT1);
  unsigned short* s_lf  = (unsigned short*)(smem + OFF_LFP);  // pitch PP
  unsigned short* s_p   = s_lf;                               // P aliases lf
  float* s_red = (float*)(smem + OFF_RED);
  unsigned short* s_rpb = (unsigned short*)(smem + OFF_RED);  // rpb after stats die

  const int tid  = threadIdx.x;
  const int lane = tid & 63;
  const int wv   = tid >> 6;     // wave 0..3
  const int quad = lane >> 4;
  const int l16  = lane & 15;

  // XCD-pair swizzle: XCD x owns contiguous windows [x*512, +512) so
  // wx-adjacent windows (sharing every 64B HBM line) hit the same L2.
  const int g   = blockIdx.x;
  const int wid = ((g & 7) << 9) | (g >> 3);   // 4096 windows, bijective
  const int b   = wid >> 10;
  const int wy  = (wid >> 5) & 31;
  const int wx  = wid & 31;
  const int h0  = wy << 3, w0 = wx << 3;

  const int t_own = tid & 63;          // token owned for load/stats (t = ty*8+tx)
  const int cg    = tid >> 6;          // channel block owner (wave-uniform)
  const int ty    = t_own >> 3, tx = t_own & 7;

  // ---- load windows (coalesced 32B row segments) + LN stats in fp32 ----
  // hfv stays live the whole kernel: it IS the residual (no re-read).
  float lfv[16], hfv[48];
  float ls = 0.f, l2 = 0.f, hs = 0.f, h2 = 0.f;
  {
    const float* p = ylf + ((size_t)(b * CLF + cg * 16) * IMG + (h0 + ty)) * IMG + (w0 + tx);
#pragma unroll
    for (int k = 0; k < 16; k++) {
      float v = p[(size_t)k * HW];
      lfv[k] = v; ls += v; l2 += v * v;
    }
  }
  {
    const float* p = yhf + ((size_t)(b * CHF + cg * 48) * IMG + (h0 + ty)) * IMG + (w0 + tx);
#pragma unroll
    for (int k = 0; k < 48; k++) {
      float v = p[(size_t)k * HW];
      hfv[k] = v; hs += v; h2 += v * v;
    }
  }
  s_red[0 * 256 + (cg << 6) + t_own] = ls;
  s_red[1 * 256 + (cg << 6) + t_own] = l2;
  s_red[2 * 256 + (cg << 6) + t_own] = hs;
  s_red[3 * 256 + (cg << 6) + t_own] = h2;
  __syncthreads();  // B1
  float su = 0.f, sq = 0.f, hu = 0.f, hq = 0.f;
#pragma unroll
  for (int gg = 0; gg < 4; gg++) {
    su += s_red[0 * 256 + (gg << 6) + t_own];
    sq += s_red[1 * 256 + (gg << 6) + t_own];
    hu += s_red[2 * 256 + (gg << 6) + t_own];
    hq += s_red[3 * 256 + (gg << 6) + t_own];
  }
  const float mu_lf = su * (1.f / 64.f);
  const float rs_lf = rsqrtf(sq * (1.f / 64.f) - mu_lf * mu_lf + 1e-5f);
  const float mu_hf = hu * (1.f / 192.f);
  const float rs_hf = rsqrtf(hq * (1.f / 192.f) - mu_hf * mu_hf + 1e-5f);

  // normalize + packed u64 bf16 stores
#pragma unroll
  for (int j = 0; j < 4; j++) {
    uint64_t w = 0;
#pragma unroll
    for (int m = 0; m < 4; m++) {
      int c = cg * 16 + j * 4 + m;
      float v = (lfv[j * 4 + m] - mu_lf) * rs_lf * glf[c] + blf[c];
      w |= (uint64_t)f2b(v) << (16 * m);
    }
    *(uint64_t*)(s_lf + t_own * PP + cg * 16 + j * 4) = w;
  }
#pragma unroll
  for (int j = 0; j < 12; j++) {
    uint64_t w = 0;
#pragma unroll
    for (int m = 0; m < 4; m++) {
      int c = cg * 48 + j * 4 + m;
      float v = (hfv[j * 4 + m] - mu_hf) * rs_hf * ghf[c] + bhf[c];
      w |= (uint64_t)f2b(v) << (16 * m);
    }
    *(uint64_t*)(s_stg + t_own * PSTG + cg * 48 + j * 4) = w;
  }
  __syncthreads();  // B2: staging visible to all waves

  // ---- pull this wave's A-fragments into REGISTERS (own 16 rows only) ----
  bf16x8 lfr0 = *(const bf16x8*)(s_lf + (wv * 16 + l16) * PP + quad * 8);
  bf16x8 lfr1 = *(const bf16x8*)(s_lf + (wv * 16 + l16) * PP + 32 + quad * 8);
  bf16x8 hfr[6];
#pragma unroll
  for (int ks = 0; ks < 6; ks++)
    hfr[ks] = *(const bf16x8*)(s_stg + (wv * 16 + l16) * PSTG + ks * 32 + quad * 8);
  __syncthreads();  // B2b: frags in regs; staging arena + lf + red reusable

  // stage RPB bf16 into the dead stats region (first read after barrier A(0))
  for (int i = tid; i < 225 * NHEAD; i += 256) s_rpb[i] = f2b(rpb[i]);

  const unsigned short* wqT = wT;           // [192][64]
  const unsigned short* wkT = wT + 12288;   // [192][192]
  const unsigned short* wvT = wT + 49152;
  const unsigned short* woT = wT + 86016;

  const int rowbase = wv * 16 + quad * 4;   // C-layout row base for this lane

  // O accumulators live across the whole head loop (AGPR-friendly)
  floatx4 oa[12];
  const floatx4 zero = {0.f, 0.f, 0.f, 0.f};
#pragma unroll
  for (int ct = 0; ct < 12; ct++) oa[ct] = zero;

  // QKV for head h into the given K/VT buffers. Q is wave-private (single buf).
  auto computeQKV = [&](int h, unsigned short* kd, unsigned short* vtd) {
#pragma unroll
    for (int nt = 0; nt < 2; nt++) {
      const int n = h * 32 + nt * 16 + l16;
      floatx4 acc = {0.f, 0.f, 0.f, 0.f};
      acc = mfma_bf16(lfr0, *(const bf16x8*)(wqT + n * 64 + quad * 8), acc);
      acc = mfma_bf16(lfr1, *(const bf16x8*)(wqT + n * 64 + 32 + quad * 8), acc);
      const float bqv = bq[n];
#pragma unroll
      for (int r = 0; r < 4; r++)
        s_q[(rowbase + r) * PQK + nt * 16 + l16] = f2b(acc[r] + bqv);
    }
#pragma unroll
    for (int nt = 0; nt < 2; nt++) {
      const int n = h * 32 + nt * 16 + l16;
      floatx4 acc = {0.f, 0.f, 0.f, 0.f};
#pragma unroll
      for (int ks = 0; ks < 6; ks++)
        acc = mfma_bf16(hfr[ks], *(const bf16x8*)(wkT + n * 192 + ks * 32 + quad * 8), acc);
      const float bkv = bk[n];
#pragma unroll
      for (int r = 0; r < 4; r++)
        kd[(rowbase + r) * PQK + nt * 16 + l16] = f2b(acc[r] + bkv);
    }
#pragma unroll
    for (int nt = 0; nt < 2; nt++) {
      const int n = h * 32 + nt * 16 + l16;
      floatx4 acc = {0.f, 0.f, 0.f, 0.f};
#pragma unroll
      for (int ks = 0; ks < 6; ks++)
        acc = mfma_bf16(hfr[ks], *(const bf16x8*)(wvT + n * 192 + ks * 32 + quad * 8), acc);
      const float bvv = bv[n];
#pragma unroll
      for (int r = 0; r < 4; r++)
        vtd[(nt * 16 + l16) * PVT + rowbase + r] = f2b(acc[r] + bvv);
    }
  };

  computeQKV(0, s_k0, s_vt0);  // prologue fill

  for (int h = 0; h < NHEAD; h++) {
    __syncthreads();  // A(h): K/VT(h) visible to all waves (h=0 also publishes rpb)
    const unsigned short* kb_ = (h & 1) ? s_k1 : s_k0;
    const unsigned short* vt_ = (h & 1) ? s_vt1 : s_vt0;

    // ---- S = Q K^T * scale + rpb bias (wave w owns query rows w*16..+15) ----
    bf16x8 aq = *(const bf16x8*)(s_q + (wv * 16 + l16) * PQK + quad * 8);
    float sv[4][4];
#pragma unroll
    for (int ct = 0; ct < 4; ct++) {
      bf16x8 kb = *(const bf16x8*)(kb_ + (ct * 16 + l16) * PQK + quad * 8);
      floatx4 acc = {0.f, 0.f, 0.f, 0.f};
      acc = mfma_bf16(aq, kb, acc);
#pragma unroll
      for (int r = 0; r < 4; r++) {
        int row = rowbase + r, col = ct * 16 + l16;
        int dy = (row >> 3) - (col >> 3) + 7;
        int dx = (row & 7) - (col & 7) + 7;
        sv[ct][r] = acc[r] * 0.17677669529663688f + b2f(s_rpb[(dy * 15 + dx) * NHEAD + h]);
      }
    }
    // ---- softmax over 64 keys: 4 in-lane + xor-shuffle over 16 lanes ----
#pragma unroll
    for (int r = 0; r < 4; r++) {
      float m = fmaxf(fmaxf(sv[0][r], sv[1][r]), fmaxf(sv[2][r], sv[3][r]));
      m = fmaxf(m, __shfl_xor(m, 1));
      m = fmaxf(m, __shfl_xor(m, 2));
      m = fmaxf(m, __shfl_xor(m, 4));
      m = fmaxf(m, __shfl_xor(m, 8));
      const float L2E = 1.4426950408889634f;
      float e0 = exp2f((sv[0][r] - m) * L2E);
      float e1 = exp2f((sv[1][r] - m) * L2E);
      float e2 = exp2f((sv[2][r] - m) * L2E);
      float e3 = exp2f((sv[3][r] - m) * L2E);
      float s = e0 + e1 + e2 + e3;
      s += __shfl_xor(s, 1);
      s += __shfl_xor(s, 2);
      s += __shfl_xor(s, 4);
      s += __shfl_xor(s, 8);
      float inv = 1.f / s;
      sv[0][r] = e0 * inv; sv[1][r] = e1 * inv; sv[2][r] = e2 * inv; sv[3][r] = e3 * inv;
    }
#pragma unroll
    for (int ct = 0; ct < 4; ct++)
#pragma unroll
      for (int r = 0; r < 4; r++)
        s_p[(rowbase + r) * PP + ct * 16 + l16] = f2b(sv[ct][r]);

    // ---- software pipeline: head h+1's QKV (independent of P/PV; writes the
    // OTHER K/VT buffer, so no conflict with any wave still reading buf h).
    // The ~30 weight loads issue here and retire under PV/O below. ----
    if (h + 1 < NHEAD)
      computeQKV(h + 1, (h & 1) ? s_k0 : s_k1, (h & 1) ? s_vt0 : s_vt1);

    // ---- PV: own P rows (same-wave LDS round trip; in-order DS) ----
    floatx4 pv0 = {0.f, 0.f, 0.f, 0.f}, pv1 = {0.f, 0.f, 0.f, 0.f};
#pragma unroll
    for (int ks = 0; ks < 2; ks++) {
      bf16x8 pa = *(const bf16x8*)(s_p + (wv * 16 + l16) * PP + ks * 32 + quad * 8);
      pv0 = mfma_bf16(pa, *(const bf16x8*)(vt_ + (0 * 16 + l16) * PVT + ks * 32 + quad * 8), pv0);
      pv1 = mfma_bf16(pa, *(const bf16x8*)(vt_ + (1 * 16 + l16) * PVT + ks * 32 + quad * 8), pv1);
    }
    // stage AO_h into s_p cols 0..31 (same-wave DS ops retire in order)
#pragma unroll
    for (int r = 0; r < 4; r++) {
      s_p[(rowbase + r) * PP + l16]      = f2b(pv0[r]);
      s_p[(rowbase + r) * PP + 16 + l16] = f2b(pv1[r]);
    }
    // ---- O += AO_h @ Wo[h*32:(h+1)*32, :]  (register accumulation) ----
    bf16x8 aoh = *(const bf16x8*)(s_p + (wv * 16 + l16) * PP + quad * 8);
#pragma unroll
    for (int ct = 0; ct < 12; ct++) {
      bf16x8 bb = *(const bf16x8*)(woT + (ct * 16 + l16) * 192 + h * 32 + quad * 8);
      oa[ct] = mfma_bf16(aoh, bb, oa[ct]);
    }
    // no barrier here: next iteration's barrier A(h+1) is the rendezvous.
  }
  __syncthreads();  // Bend: all waves done reading K/VT/Q/rpb of head 5

  // ---- epilogue: stage O + bo (compute mapping) into the arena, pitch PSTG ----
#pragma unroll
  for (int ct = 0; ct < 12; ct++) {
    const int col = ct * 16 + l16;
    const float bov = bo[col];
#pragma unroll
    for (int r = 0; r < 4; r++)
      s_stg[(rowbase + r) * PSTG + col] = f2b(oa[ct][r] + bov);
  }
  __syncthreads();  // Bstg: cross-wave gather follows

  // ---- store with the LOAD mapping: residual straight from hfv registers ----
  {
    float* po = out + ((size_t)(b * CHF + cg * 48) * IMG + (h0 + ty)) * IMG + (w0 + tx);
#pragma unroll
    for (int j = 0; j < 12; j++) {
      uint64_t w = *(const uint64_t*)(s_stg + t_own * PSTG + cg * 48 + j * 4);
#pragma unroll
      for (int m = 0; m < 4; m++) {
        float o = b2f((unsigned short)(w >> (16 * m)));
        po[(size_t)(j * 4 + m) * HW] = o + hfv[j * 4 + m];
      }
    }
  }
}

extern "C" void kernel_launch(void* const* d_in, const int* in_sizes, int n_in,
                              void* d_out, int out_size, void* d_ws, size_t ws_size,
                              hipStream_t stream) {
  const float* ylf = (const float*)d_in[0];
  const float* yhf = (const float*)d_in[1];
  const float* glf = (const float*)d_in[2];
  const float* blf = (const float*)d_in[3];
  const float* ghf = (const float*)d_in[4];
  const float* bhf = (const float*)d_in[5];
  const float* Wq  = (const float*)d_in[6];
  const float* bq  = (const float*)d_in[7];
  const float* Wk  = (const float*)d_in[8];
  const float* bk  = (const float*)d_in[9];
  const float* Wv  = (const float*)d_in[10];
  const float* bv  = (const float*)d_in[11];
  const float* Wo  = (const float*)d_in[12];
  const float* bo  = (const float*)d_in[13];
  const float* rpb = (const float*)d_in[14];
  unsigned short* wT = (unsigned short*)d_ws;  // 122880 bf16 = 245760 B

  wca_prep<<<480, 256, 0, stream>>>(Wq, Wk, Wv, Wo, wT);
  wca_main<<<4096, 256, 0, stream>>>(ylf, yhf, glf, blf, ghf, bhf,
                                     bq, bk, bv, bo, rpb, wT, (float*)d_out);
}

// Round 5
// 640.531 us; speedup vs baseline: 1.6286x; 1.5727x over previous
//
#include <hip/hip_runtime.h>
#include <cstdint>
#include <cstddef>

#define DEVI __device__ __forceinline__

typedef __bf16 bf16x8 __attribute__((ext_vector_type(8)));
typedef float  floatx4 __attribute__((ext_vector_type(4)));

constexpr int NHEAD = 6;
constexpr int CLF = 64, CHF = 192;
constexpr int IMG = 256;
constexpr int HW  = IMG * IMG;

// LDS pitches (bf16 elements). Row byte-stride multiple of 16 (ds_read_b128).
constexpr int P_WQ  = 72;   // staged WqT-all rows (64+8)
constexpr int P_WKV = 200;  // staged WkT/WvT slice rows (192+8); == load-phase hf pitch
constexpr int P_WO  = 40;   // staged WoT slice rows (32+8)
constexpr int PQK = 40;     // K tile (64 x 32+8)
constexpr int PVT = 72;     // V^T (32 x 64+8)
constexpr int PP  = 72;     // lf staging / P / AO (64 x 64+8)

// LDS map (bytes). Aliasing timeline:
//   [load]    WKV region = hf_n staging (64 x 200);  P region = lf staging;  RED = LN stats
//   [Q-all]   WKV+WO head = WqT-all staged (192 x 72 = 27648B);  RED = rpb bf16
//   [heads]   WKV = WkT|WvT slice (2 x 32 x 200);  WO = WoT slice (192 x 40)
//   [epilog]  WKV region = O staging (64 x 200)
constexpr int OFF_WKV = 0;      // 25600
constexpr int OFF_WO  = 25600;  // 15360
constexpr int OFF_K   = 40960;  // 5120
constexpr int OFF_VT  = 46080;  // 4608
constexpr int OFF_P   = 50688;  // 9216
constexpr int OFF_RED = 59904;  // 4096
constexpr int SMEM_BYTES = 64000;  // x2 blocks/CU = 128000 <= 163840

DEVI unsigned short f2b(float f) {  // fp32 -> bf16 RNE
  unsigned u = __float_as_uint(f);
  u += 0x7fffu + ((u >> 16) & 1u);
  return (unsigned short)(u >> 16);
}
DEVI float b2f(unsigned short s) { return __uint_as_float(((unsigned)s) << 16); }

DEVI floatx4 mfma_bf16(bf16x8 a, bf16x8 b, floatx4 c) {
  return __builtin_amdgcn_mfma_f32_16x16x32_bf16(a, b, c, 0, 0, 0);
}

// ---- prep: W[k][n] fp32 -> W^T[n][k] bf16 into workspace ----
__global__ void wca_prep(const float* __restrict__ Wq, const float* __restrict__ Wk,
                         const float* __restrict__ Wv, const float* __restrict__ Wo,
                         unsigned short* __restrict__ wT) {
  int i = blockIdx.x * 256 + threadIdx.x;  // grid covers exactly 122880
  if (i < 12288) {                         // WqT: 192 x 64
    int n = i >> 6, k = i & 63;
    wT[i] = f2b(Wq[k * 192 + n]);
  } else if (i < 49152) {                  // WkT: 192 x 192
    int j = i - 12288, n = j / 192, k = j - n * 192;
    wT[i] = f2b(Wk[k * 192 + n]);
  } else if (i < 86016) {                  // WvT
    int j = i - 49152, n = j / 192, k = j - n * 192;
    wT[i] = f2b(Wv[k * 192 + n]);
  } else {                                 // WoT
    int j = i - 86016, n = j / 192, k = j - n * 192;
    wT[i] = f2b(Wo[k * 192 + n]);
  }
}

__global__ __launch_bounds__(256, 2) void wca_main(
    const float* __restrict__ ylf, const float* __restrict__ yhf,
    const float* __restrict__ glf, const float* __restrict__ blf,
    const float* __restrict__ ghf, const float* __restrict__ bhf,
    const float* __restrict__ bq,  const float* __restrict__ bk,
    const float* __restrict__ bv,  const float* __restrict__ bo,
    const float* __restrict__ rpb, const unsigned short* __restrict__ wT,
    float* __restrict__ out) {
  __shared__ __align__(16) char smem[SMEM_BYTES];
  unsigned short* s_wkv = (unsigned short*)(smem + OFF_WKV);  // weight slices / hf stg / O stg
  unsigned short* s_wq  = s_wkv;                              // WqT-all (spills into WO region)
  unsigned short* s_wo  = (unsigned short*)(smem + OFF_WO);
  unsigned short* s_k   = (unsigned short*)(smem + OFF_K);
  unsigned short* s_vt  = (unsigned short*)(smem + OFF_VT);
  unsigned short* s_lf  = (unsigned short*)(smem + OFF_P);    // lf staging, then P/AO
  unsigned short* s_p   = s_lf;
  float* s_red = (float*)(smem + OFF_RED);
  unsigned short* s_rpb = (unsigned short*)(smem + OFF_RED);  // rpb after stats die

  const int tid  = threadIdx.x;
  const int lane = tid & 63;
  const int wv   = tid >> 6;     // wave 0..3
  const int quad = lane >> 4;
  const int l16  = lane & 15;

  // XCD-pair swizzle: XCD x owns contiguous windows [x*512, +512) so
  // wx-adjacent windows (sharing every 64B HBM line) hit the same L2.
  const int g   = blockIdx.x;
  const int wid = ((g & 7) << 9) | (g >> 3);   // 4096 windows, bijective
  const int b   = wid >> 10;
  const int wy  = (wid >> 5) & 31;
  const int wx  = wid & 31;
  const int h0  = wy << 3, w0 = wx << 3;

  const int t_own = tid & 63;          // token owned for load/stats (t = ty*8+tx)
  const int cg    = tid >> 6;          // channel block owner (wave-uniform)
  const int ty    = t_own >> 3, tx = t_own & 7;

  // ---- load windows (coalesced 32B row segments) + LN stats in fp32 ----
  float lfv[16], hfv[48];
  float ls = 0.f, l2 = 0.f, hs = 0.f, h2 = 0.f;
  {
    const float* p = ylf + ((size_t)(b * CLF + cg * 16) * IMG + (h0 + ty)) * IMG + (w0 + tx);
#pragma unroll
    for (int k = 0; k < 16; k++) {
      float v = p[(size_t)k * HW];
      lfv[k] = v; ls += v; l2 += v * v;
    }
  }
  {
    const float* p = yhf + ((size_t)(b * CHF + cg * 48) * IMG + (h0 + ty)) * IMG + (w0 + tx);
#pragma unroll
    for (int k = 0; k < 48; k++) {
      float v = p[(size_t)k * HW];
      hfv[k] = v; hs += v; h2 += v * v;
    }
  }
  s_red[0 * 256 + (cg << 6) + t_own] = ls;
  s_red[1 * 256 + (cg << 6) + t_own] = l2;
  s_red[2 * 256 + (cg << 6) + t_own] = hs;
  s_red[3 * 256 + (cg << 6) + t_own] = h2;
  __syncthreads();  // B1
  float su = 0.f, sq = 0.f, hu = 0.f, hq = 0.f;
#pragma unroll
  for (int gg = 0; gg < 4; gg++) {
    su += s_red[0 * 256 + (gg << 6) + t_own];
    sq += s_red[1 * 256 + (gg << 6) + t_own];
    hu += s_red[2 * 256 + (gg << 6) + t_own];
    hq += s_red[3 * 256 + (gg << 6) + t_own];
  }
  const float mu_lf = su * (1.f / 64.f);
  const float rs_lf = rsqrtf(sq * (1.f / 64.f) - mu_lf * mu_lf + 1e-5f);
  const float mu_hf = hu * (1.f / 192.f);
  const float rs_hf = rsqrtf(hq * (1.f / 192.f) - mu_hf * mu_hf + 1e-5f);

  // normalize + packed u64 bf16 stores
#pragma unroll
  for (int j = 0; j < 4; j++) {
    uint64_t w = 0;
#pragma unroll
    for (int m = 0; m < 4; m++) {
      int c = cg * 16 + j * 4 + m;
      float v = (lfv[j * 4 + m] - mu_lf) * rs_lf * glf[c] + blf[c];
      w |= (uint64_t)f2b(v) << (16 * m);
    }
    *(uint64_t*)(s_lf + t_own * PP + cg * 16 + j * 4) = w;
  }
#pragma unroll
  for (int j = 0; j < 12; j++) {
    uint64_t w = 0;
#pragma unroll
    for (int m = 0; m < 4; m++) {
      int c = cg * 48 + j * 4 + m;
      float v = (hfv[j * 4 + m] - mu_hf) * rs_hf * ghf[c] + bhf[c];
      w |= (uint64_t)f2b(v) << (16 * m);
    }
    *(uint64_t*)(s_wkv + t_own * P_WKV + cg * 48 + j * 4) = w;
  }
  __syncthreads();  // B2: staging visible to all waves

  // ---- pull this wave's A-fragments into REGISTERS (own 16 rows only) ----
  bf16x8 lfr0 = *(const bf16x8*)(s_lf + (wv * 16 + l16) * PP + quad * 8);
  bf16x8 lfr1 = *(const bf16x8*)(s_lf + (wv * 16 + l16) * PP + 32 + quad * 8);
  bf16x8 hfr[6];
#pragma unroll
  for (int ks = 0; ks < 6; ks++)
    hfr[ks] = *(const bf16x8*)(s_wkv + (wv * 16 + l16) * P_WKV + ks * 32 + quad * 8);
  __syncthreads();  // B2b: frags in regs; staging regions reusable

  const unsigned short* wqT = wT;           // [192][64]
  const unsigned short* wkT = wT + 12288;   // [192][192]
  const unsigned short* wvT = wT + 49152;
  const unsigned short* woT = wT + 86016;

  // ---- stage WqT-all (contiguous 1KB/wave-instr copies, NO gathers) + rpb ----
#pragma unroll
  for (int i = 0; i < 6; i++) {
    int p = i * 256 + tid;            // 1536 pieces of 16B (192 rows x 8)
    int n = p >> 3, sub = p & 7;
    *(uint4*)(s_wq + n * P_WQ + sub * 8) = *(const uint4*)(wqT + n * 64 + sub * 8);
  }
  for (int i = tid; i < 225 * NHEAD; i += 256) s_rpb[i] = f2b(rpb[i]);
  __syncthreads();  // B3: WqT-all + rpb staged

  const int rowbase = wv * 16 + quad * 4;   // C-layout row base for this lane

  // ---- Q for ALL heads upfront; fragments kept in registers (24 VGPR) ----
  bf16x8 aq[NHEAD];
#pragma unroll
  for (int h = 0; h < NHEAD; h++) {
#pragma unroll
    for (int nt = 0; nt < 2; nt++) {
      const int n = h * 32 + nt * 16 + l16;
      floatx4 acc = {0.f, 0.f, 0.f, 0.f};
      acc = mfma_bf16(lfr0, *(const bf16x8*)(s_wq + n * P_WQ + quad * 8), acc);
      acc = mfma_bf16(lfr1, *(const bf16x8*)(s_wq + n * P_WQ + 32 + quad * 8), acc);
      const float bqv = bq[n];
#pragma unroll
      for (int r = 0; r < 4; r++)
        s_p[(rowbase + r) * PP + nt * 16 + l16] = f2b(acc[r] + bqv);
    }
    // wave-local LDS round trip (in-order DS): fragment for this wave's rows
    aq[h] = *(const bf16x8*)(s_p + (wv * 16 + l16) * PP + quad * 8);
  }
  __syncthreads();  // B4: all waves done reading WqT region (it gets overwritten next)

  // coalesced staging of the per-head WkT/WvT slices (contiguous in wT)
  auto stageKV = [&](int h) {
    const unsigned short* sk = wkT + h * 6144;   // 32 rows x 192, contiguous
    const unsigned short* sv = wvT + h * 6144;
#pragma unroll
    for (int i = 0; i < 3; i++) {
      int p = i * 256 + tid;          // 768 pieces of 16B
      int nl = p / 24, sub = p - nl * 24;
      *(uint4*)(s_wkv + nl * P_WKV + sub * 8) = *(const uint4*)(sk + nl * 192 + sub * 8);
      *(uint4*)(s_wkv + (32 + nl) * P_WKV + sub * 8) = *(const uint4*)(sv + nl * 192 + sub * 8);
    }
  };

  stageKV(0);
  __syncthreads();  // S(0): KV(0) staged

  // O accumulators live across the whole head loop
  floatx4 oa[12];
  const floatx4 zero = {0.f, 0.f, 0.f, 0.f};
#pragma unroll
  for (int ct = 0; ct < 12; ct++) oa[ct] = zero;

#pragma unroll
  for (int h = 0; h < NHEAD; h++) {
    // ---- K_h -> s_k (A from hfr regs, B from staged LDS) ----
#pragma unroll
    for (int nt = 0; nt < 2; nt++) {
      const int n = h * 32 + nt * 16 + l16;
      const int nl = nt * 16 + l16;
      floatx4 acc = {0.f, 0.f, 0.f, 0.f};
#pragma unroll
      for (int ks = 0; ks < 6; ks++)
        acc = mfma_bf16(hfr[ks], *(const bf16x8*)(s_wkv + nl * P_WKV + ks * 32 + quad * 8), acc);
      const float bkv = bk[n];
#pragma unroll
      for (int r = 0; r < 4; r++)
        s_k[(rowbase + r) * PQK + nt * 16 + l16] = f2b(acc[r] + bkv);
    }
    // ---- V_h -> s_vt (transposed store) ----
#pragma unroll
    for (int nt = 0; nt < 2; nt++) {
      const int n = h * 32 + nt * 16 + l16;
      const int nl = nt * 16 + l16;
      floatx4 acc = {0.f, 0.f, 0.f, 0.f};
#pragma unroll
      for (int ks = 0; ks < 6; ks++)
        acc = mfma_bf16(hfr[ks], *(const bf16x8*)(s_wkv + (32 + nl) * P_WKV + ks * 32 + quad * 8), acc);
      const float bvv = bv[n];
#pragma unroll
      for (int r = 0; r < 4; r++)
        s_vt[(nt * 16 + l16) * PVT + rowbase + r] = f2b(acc[r] + bvv);
    }
    __syncthreads();  // A(h): s_k/s_vt visible; WKV slice dead for ALL waves

    // ---- stage WoT slice (h) + prefetch KV(h+1); retires under the attn math ----
#pragma unroll
    for (int i = 0; i < 3; i++) {
      int p = i * 256 + tid;          // 768 pieces: 192 rows x 4
      int n = p >> 2, sub = p & 3;
      *(uint4*)(s_wo + n * P_WO + sub * 8) = *(const uint4*)(woT + n * 192 + h * 32 + sub * 8);
    }
    if (h + 1 < NHEAD) stageKV(h + 1);

    // ---- S = Q K^T * scale + rpb (wave w owns query rows w*16..+15) ----
    float sv[4][4];
#pragma unroll
    for (int ct = 0; ct < 4; ct++) {
      bf16x8 kb = *(const bf16x8*)(s_k + (ct * 16 + l16) * PQK + quad * 8);
      floatx4 acc = {0.f, 0.f, 0.f, 0.f};
      acc = mfma_bf16(aq[h], kb, acc);
#pragma unroll
      for (int r = 0; r < 4; r++) {
        int row = rowbase + r, col = ct * 16 + l16;
        int dy = (row >> 3) - (col >> 3) + 7;
        int dx = (row & 7) - (col & 7) + 7;
        sv[ct][r] = acc[r] * 0.17677669529663688f + b2f(s_rpb[(dy * 15 + dx) * NHEAD + h]);
      }
    }
    // ---- softmax over 64 keys ----
#pragma unroll
    for (int r = 0; r < 4; r++) {
      float m = fmaxf(fmaxf(sv[0][r], sv[1][r]), fmaxf(sv[2][r], sv[3][r]));
      m = fmaxf(m, __shfl_xor(m, 1));
      m = fmaxf(m, __shfl_xor(m, 2));
      m = fmaxf(m, __shfl_xor(m, 4));
      m = fmaxf(m, __shfl_xor(m, 8));
      const float L2E = 1.4426950408889634f;
      float e0 = exp2f((sv[0][r] - m) * L2E);
      float e1 = exp2f((sv[1][r] - m) * L2E);
      float e2 = exp2f((sv[2][r] - m) * L2E);
      float e3 = exp2f((sv[3][r] - m) * L2E);
      float s = e0 + e1 + e2 + e3;
      s += __shfl_xor(s, 1);
      s += __shfl_xor(s, 2);
      s += __shfl_xor(s, 4);
      s += __shfl_xor(s, 8);
      float inv = 1.f / s;
      sv[0][r] = e0 * inv; sv[1][r] = e1 * inv; sv[2][r] = e2 * inv; sv[3][r] = e3 * inv;
    }
#pragma unroll
    for (int ct = 0; ct < 4; ct++)
#pragma unroll
      for (int r = 0; r < 4; r++)
        s_p[(rowbase + r) * PP + ct * 16 + l16] = f2b(sv[ct][r]);

    // ---- PV (wave-local P round trip; in-order DS) ----
    floatx4 pv0 = {0.f, 0.f, 0.f, 0.f}, pv1 = {0.f, 0.f, 0.f, 0.f};
#pragma unroll
    for (int ks = 0; ks < 2; ks++) {
      bf16x8 pa = *(const bf16x8*)(s_p + (wv * 16 + l16) * PP + ks * 32 + quad * 8);
      pv0 = mfma_bf16(pa, *(const bf16x8*)(s_vt + (0 * 16 + l16) * PVT + ks * 32 + quad * 8), pv0);
      pv1 = mfma_bf16(pa, *(const bf16x8*)(s_vt + (1 * 16 + l16) * PVT + ks * 32 + quad * 8), pv1);
    }
#pragma unroll
    for (int r = 0; r < 4; r++) {
      s_p[(rowbase + r) * PP + l16]      = f2b(pv0[r]);
      s_p[(rowbase + r) * PP + 16 + l16] = f2b(pv1[r]);
    }
    bf16x8 aoh = *(const bf16x8*)(s_p + (wv * 16 + l16) * PP + quad * 8);
    __syncthreads();  // A2(h): WoT(h) + KV(h+1) staged/visible; s_k/s_vt reads done

    // ---- O += AO_h @ Wo[h*32:+32, :] (B-frags from staged LDS) ----
#pragma unroll
    for (int ct = 0; ct < 12; ct++) {
      bf16x8 bb = *(const bf16x8*)(s_wo + (ct * 16 + l16) * P_WO + quad * 8);
      oa[ct] = mfma_bf16(aoh, bb, oa[ct]);
    }
    // next iteration's compute reads KV(h+1), already published by A2(h).
    // staging writes for h+1 (after A(h+1)) can't pass A(h+1) -> no extra barrier.
  }

  // ---- epilogue: stage O + bo (compute mapping) into WKV region, pitch 200 ----
  // (WKV weight reads all ended before A(5); WO reads are this wave's own, done above)
#pragma unroll
  for (int ct = 0; ct < 12; ct++) {
    const int col = ct * 16 + l16;
    const float bov = bo[col];
#pragma unroll
    for (int r = 0; r < 4; r++)
      s_wkv[(rowbase + r) * P_WKV + col] = f2b(oa[ct][r] + bov);
  }
  __syncthreads();  // Bstg: cross-wave gather follows

  // ---- coalesced float4 store; residual re-read from global (L3-warm, same lines) ----
#pragma unroll
  for (int k = 0; k < 12; k++) {
    int chunk = k * 256 + tid;       // 3072 chunks of 4 floats = 192ch x 64tok
    int c   = chunk >> 4;
    int sub = chunk & 15;
    int yy  = sub >> 1;
    int x4  = (sub & 1) << 2;
    int t0  = (yy << 3) + x4;
    size_t gidx = ((size_t)(b * CHF + c) * IMG + (h0 + yy)) * IMG + w0 + x4;
    float4 res = *(const float4*)(yhf + gidx);
    float4 v;
    v.x = b2f(s_wkv[(t0 + 0) * P_WKV + c]) + res.x;
    v.y = b2f(s_wkv[(t0 + 1) * P_WKV + c]) + res.y;
    v.z = b2f(s_wkv[(t0 + 2) * P_WKV + c]) + res.z;
    v.w = b2f(s_wkv[(t0 + 3) * P_WKV + c]) + res.w;
    *(float4*)(out + gidx) = v;
  }
}

extern "C" void kernel_launch(void* const* d_in, const int* in_sizes, int n_in,
                              void* d_out, int out_size, void* d_ws, size_t ws_size,
                              hipStream_t stream) {
  const float* ylf = (const float*)d_in[0];
  const float* yhf = (const float*)d_in[1];
  const float* glf = (const float*)d_in[2];
  const float* blf = (const float*)d_in[3];
  const float* ghf = (const float*)d_in[4];
  const float* bhf = (const float*)d_in[5];
  const float* Wq  = (const float*)d_in[6];
  const float* bq  = (const float*)d_in[7];
  const float* Wk  = (const float*)d_in[8];
  const float* bk  = (const float*)d_in[9];
  const float* Wv  = (const float*)d_in[10];
  const float* bv  = (const float*)d_in[11];
  const float* Wo  = (const float*)d_in[12];
  const float* bo  = (const float*)d_in[13];
  const float* rpb = (const float*)d_in[14];
  unsigned short* wT = (unsigned short*)d_ws;  // 122880 bf16 = 245760 B

  wca_prep<<<480, 256, 0, stream>>>(Wq, Wk, Wv, Wo, wT);
  wca_main<<<4096, 256, 0, stream>>>(ylf, yhf, glf, blf, ghf, bhf,
                                     bq, bk, bv, bo, rpb, wT, (float*)d_out);
}